// Round 9
// baseline (827.908 us; speedup 1.0000x reference)
//
#include <hip/hip_runtime.h>
#include <math.h>

#define DN 256
#define LN_EPS 1e-5f
#define BSHIFT 6                   // 64 rows per bucket (needs N <= 65536, N < 2^17)

using f32x4  = __attribute__((ext_vector_type(4))) float;
using short8 = __attribute__((ext_vector_type(8))) short;

__device__ __forceinline__ ushort f2bf(float f) {
    uint u = __float_as_uint(f);
    u += 0x7fff + ((u >> 16) & 1);           // round-to-nearest-even
    return (ushort)(u >> 16);
}
__device__ __forceinline__ float bf2f(ushort h) { return __uint_as_float((uint)h << 16); }
__device__ __forceinline__ float bf_lo(uint u) { return __uint_as_float(u << 16); }
__device__ __forceinline__ float bf_hi(uint u) { return __uint_as_float(u & 0xffff0000u); }

// ---------------- x -> bf16 cast ----------------
__global__ __launch_bounds__(256) void cast_f32_bf16(const float* __restrict__ src,
                                                     ushort* __restrict__ dst, int n8) {
    int i = blockIdx.x * 256 + threadIdx.x;
    if (i >= n8) return;
    float4 a = reinterpret_cast<const float4*>(src)[2 * i];
    float4 b = reinterpret_cast<const float4*>(src)[2 * i + 1];
    uint4 o;
    o.x = (uint)f2bf(a.x) | ((uint)f2bf(a.y) << 16);
    o.y = (uint)f2bf(a.z) | ((uint)f2bf(a.w) << 16);
    o.z = (uint)f2bf(b.x) | ((uint)f2bf(b.y) << 16);
    o.w = (uint)f2bf(b.z) | ((uint)f2bf(b.w) << 16);
    reinterpret_cast<uint4*>(dst)[i] = o;
}

// ---------------- W split cast: f32 -> bf16 hi + bf16 lo ----------------
__global__ __launch_bounds__(256) void cast_split(const float* __restrict__ src,
                                                  ushort* __restrict__ hi,
                                                  ushort* __restrict__ lo, int n4) {
    int i = blockIdx.x * 256 + threadIdx.x;
    if (i >= n4) return;
    float4 a = reinterpret_cast<const float4*>(src)[i];
    ushort h0 = f2bf(a.x), h1 = f2bf(a.y), h2 = f2bf(a.z), h3 = f2bf(a.w);
    uint2 ho, lu;
    ho.x = (uint)h0 | ((uint)h1 << 16);
    ho.y = (uint)h2 | ((uint)h3 << 16);
    lu.x = (uint)f2bf(a.x - bf2f(h0)) | ((uint)f2bf(a.y - bf2f(h1)) << 16);
    lu.y = (uint)f2bf(a.z - bf2f(h2)) | ((uint)f2bf(a.w - bf2f(h3)) << 16);
    reinterpret_cast<uint2*>(hi)[i] = ho;
    reinterpret_cast<uint2*>(lo)[i] = lu;
}

// ---------------- CSR construction (bucketed counting sort) ----------------
// pass 1: per-row degree (rp) + per-bucket histogram (LDS-staged)
__global__ __launch_bounds__(256) void deg_bucket_count(const int* __restrict__ ei,
                                                        int* __restrict__ rp,
                                                        int* __restrict__ bcnt, int E) {
    __shared__ int h[1024];
    for (int i = threadIdx.x; i < 1024; i += 256) h[i] = 0;
    __syncthreads();
    int stride = gridDim.x * 256;
    for (int e = blockIdx.x * 256 + threadIdx.x; e < E; e += stride) {
        int r = ei[e];
        atomicAdd(&rp[r], 1);
        atomicAdd(&h[r >> BSHIFT], 1);
    }
    __syncthreads();
    for (int i = threadIdx.x; i < 1024; i += 256)
        if (h[i]) atomicAdd(&bcnt[i], h[i]);
}

// single-block exclusive scan of bcnt[0..nb) -> boff, bcur; boff[nb]=total
__global__ __launch_bounds__(256) void scan_buckets(const int* __restrict__ bcnt,
                                                    int* __restrict__ boff,
                                                    int* __restrict__ bcur, int nb) {
    __shared__ int wsum[4];
    __shared__ int carry_s;
    int tid = threadIdx.x, lane = tid & 63, w = tid >> 6;
    if (tid == 0) carry_s = 0;
    __syncthreads();
    for (int base = 0; base < nb; base += 256) {
        int i = base + tid;
        int v = (i < nb) ? bcnt[i] : 0;
        int s = v;
#pragma unroll
        for (int m = 1; m < 64; m <<= 1) {
            int t = __shfl_up(s, m);
            if (lane >= m) s += t;
        }
        if (lane == 63) wsum[w] = s;
        __syncthreads();
        int woff = 0;
        for (int k = 0; k < w; ++k) woff += wsum[k];
        int carry = carry_s;
        __syncthreads();
        if (i < nb) { boff[i] = carry + woff + s - v; bcur[i] = carry + woff + s - v; }
        if (tid == 255) carry_s = carry + woff + s;
        __syncthreads();
    }
    if (tid == 0) boff[nb] = carry_s;
}

// 3-phase parallel exclusive scan of rp[0..N) (in place); also sets rp[N]=E
__global__ __launch_bounds__(256) void scan_phase1(int* __restrict__ rp,
                                                   int* __restrict__ part, int N) {
    __shared__ int wsum[4];
    int tid = threadIdx.x, lane = tid & 63, w = tid >> 6;
    int i = blockIdx.x * 256 + tid;
    int v = (i < N) ? rp[i] : 0;
    int s = v;
#pragma unroll
    for (int m = 1; m < 64; m <<= 1) {
        int t = __shfl_up(s, m);
        if (lane >= m) s += t;
    }
    if (lane == 63) wsum[w] = s;
    __syncthreads();
    int woff = 0;
    for (int k = 0; k < w; ++k) woff += wsum[k];
    if (i < N) rp[i] = woff + s - v;
    if (tid == 255) part[blockIdx.x] = woff + s;
}

__global__ __launch_bounds__(256) void scan_phase2(int* __restrict__ part, int nblk) {
    __shared__ int wsum[4];
    int tid = threadIdx.x, lane = tid & 63, w = tid >> 6;
    int v = (tid < nblk) ? part[tid] : 0;
    int s = v;
#pragma unroll
    for (int m = 1; m < 64; m <<= 1) {
        int t = __shfl_up(s, m);
        if (lane >= m) s += t;
    }
    if (lane == 63) wsum[w] = s;
    __syncthreads();
    int woff = 0;
    for (int k = 0; k < w; ++k) woff += wsum[k];
    if (tid < nblk) part[tid] = woff + s - v;
}

__global__ __launch_bounds__(256) void scan_phase3(int* __restrict__ rp,
                                                   const int* __restrict__ part,
                                                   int N, int E) {
    int i = blockIdx.x * 256 + threadIdx.x;
    if (i < N) rp[i] += part[blockIdx.x];
    if (blockIdx.x == 0 && threadIdx.x == 0) rp[N] = E;
}

// pass 2: scatter packed records into bucket regions (write-local: ~nb hot lines)
__global__ __launch_bounds__(256) void bucket_fill(const int* __restrict__ ei,
                                                   int* __restrict__ bcur,
                                                   uint* __restrict__ brec, int E) {
    int e = blockIdx.x * 256 + threadIdx.x;
    if (e >= E) return;
    int r = ei[e], c = ei[E + e];
    int pos = atomicAdd(&bcur[r >> BSHIFT], 1);
    brec[pos] = ((uint)(r & 63) << 17) | (uint)c;   // needs col < 2^17
}

// pass 3: one block per bucket; LDS cursors over its 64 rows; csr writes land
// in a contiguous ~8KB window per block
__global__ __launch_bounds__(256) void csr_from_buckets(const uint* __restrict__ brec,
                                                        const int* __restrict__ boff,
                                                        const int* __restrict__ rp,
                                                        int* __restrict__ csr_col,
                                                        int N) {
    __shared__ int cur[64];
    int b = blockIdx.x;
    int r0 = b << BSHIFT;
    int tid = threadIdx.x;
    if (tid < 64) cur[tid] = (r0 + tid < N) ? rp[r0 + tid] : 0;
    __syncthreads();
    int s = boff[b], e2 = boff[b + 1];
    for (int i = s + tid; i < e2; i += 256) {
        uint rec = brec[i];
        int rl = rec >> 17, c = (int)(rec & 0x1ffff);
        int pos = atomicAdd(&cur[rl], 1);
        csr_col[pos] = c;
    }
}

// ---------------- aggregation: y = self(fp32) + mean(neighbors bf16) ----------------
// rp is a clean exclusive scan with rp[N]=E. Writes split bf16 PACKED rows
// [256 hi][256 lo] (1024B = fp32 row). out_packed may alias xf_self.
__global__ __launch_bounds__(256) void aggregate_packed(const float* xf_self,
                                                        const ushort* __restrict__ xb_neigh,
                                                        const int* __restrict__ rp,
                                                        const int* __restrict__ csr_col,
                                                        ushort* out_packed, int N) {
    int wid  = (blockIdx.x * 256 + threadIdx.x) >> 6;
    int lane = threadIdx.x & 63;
    if (wid >= N) return;
    int start = rp[wid];
    int end   = rp[wid + 1];

    float4 xv = reinterpret_cast<const float4*>(xf_self + (size_t)wid * DN)[lane];

    float a0 = 0.f, a1 = 0.f, a2 = 0.f, a3 = 0.f;
    int j = start;
    for (; j + 8 <= end; j += 8) {
        uint2 v[8];
#pragma unroll
        for (int q = 0; q < 8; ++q) {
            int c = csr_col[j + q];
            v[q] = *reinterpret_cast<const uint2*>(xb_neigh + (size_t)c * DN + lane * 4);
        }
#pragma unroll
        for (int q = 0; q < 8; ++q) {
            a0 += bf_lo(v[q].x); a1 += bf_hi(v[q].x);
            a2 += bf_lo(v[q].y); a3 += bf_hi(v[q].y);
        }
    }
    for (; j < end; ++j) {
        int c = csr_col[j];
        uint2 v = *reinterpret_cast<const uint2*>(xb_neigh + (size_t)c * DN + lane * 4);
        a0 += bf_lo(v.x); a1 += bf_hi(v.x); a2 += bf_lo(v.y); a3 += bf_hi(v.y);
    }
    int deg = end - start;
    float inv = (deg > 0) ? 1.0f / (float)deg : 0.0f;
    float y0 = xv.x + a0 * inv, y1 = xv.y + a1 * inv;
    float y2 = xv.z + a2 * inv, y3 = xv.w + a3 * inv;
    ushort h0 = f2bf(y0), h1 = f2bf(y1), h2 = f2bf(y2), h3 = f2bf(y3);
    uint2 ho, lu;
    ho.x = (uint)h0 | ((uint)h1 << 16);
    ho.y = (uint)h2 | ((uint)h3 << 16);
    lu.x = (uint)f2bf(y0 - bf2f(h0)) | ((uint)f2bf(y1 - bf2f(h1)) << 16);
    lu.y = (uint)f2bf(y2 - bf2f(h2)) | ((uint)f2bf(y3 - bf2f(h3)) << 16);
    ushort* row = out_packed + (size_t)wid * 512;
    *reinterpret_cast<uint2*>(row + lane * 4) = ho;          // hi section [0,256)
    *reinterpret_cast<uint2*>(row + 256 + lane * 4) = lu;    // lo section [256,512)
}

// ---------------- split-precision MFMA GEMM + LayerNorm + SiLU ----------------
// h = (yhi+ylo) @ (Whi+Wlo)^T + b, dropping only the ylo*Wlo (eps^2) term.
// 512 threads = 8 waves, 128 rows/block. W in 8 x 32KB K-slices (4 hi + 4 lo),
// double-buffered ping-pong LDS, 1 barrier per slice, loads overlap MFMA.
__global__ __launch_bounds__(512) void gemm_ln_silu_mfma(
        const ushort* yb, const ushort* __restrict__ whi, const ushort* __restrict__ wlo,
        const float* __restrict__ bias, const float* __restrict__ gam,
        const float* __restrict__ bet,
        float* outf, ushort* __restrict__ outb, int N) {
    __shared__ uint4 wl4[2][2048];              // 2 x 32 KB ping-pong

    int tid = threadIdx.x;
    int w = tid >> 6, lane = tid & 63;
    int g = lane >> 4, c0 = lane & 15;
    int n0 = blockIdx.x * 128;

    int arow = n0 + w * 16 + c0;
    bool av = arow < N;
    const ushort* ah = yb + (size_t)arow * 512 + g * 8;
    short8 zz = {0, 0, 0, 0, 0, 0, 0, 0};
    short8 ahi[8], alo[8];
#pragma unroll
    for (int kk = 0; kk < 8; ++kk) {
        ahi[kk] = av ? *reinterpret_cast<const short8*>(ah + kk * 32) : zz;
        alo[kk] = av ? *reinterpret_cast<const short8*>(ah + 256 + kk * 32) : zz;
    }

    f32x4 acc[16];
#pragma unroll
    for (int t = 0; t < 16; ++t) acc[t] = (f32x4){0.f, 0.f, 0.f, 0.f};

    uint4 streg[4];
#pragma unroll
    for (int i = 0; i < 4; ++i) {
        int chunk = tid + 512 * i;
        int j = chunk >> 3, kb = chunk & 7;
        streg[i] = *reinterpret_cast<const uint4*>(whi + (size_t)j * DN + kb * 8);
    }
#pragma unroll
    for (int i = 0; i < 4; ++i) {
        int chunk = tid + 512 * i;
        int j = chunk >> 3, kb = chunk & 7;
        int dst = ((j * 128 + kb * 16) ^ ((j & 7) << 4)) >> 4;
        wl4[0][dst] = streg[i];
    }
    __syncthreads();

#pragma unroll
    for (int st = 0; st < 8; ++st) {
        int cur = st & 1;
        if (st < 7) {
            const ushort* wsrc = (st + 1 < 4) ? whi : wlo;
            int k0 = ((st + 1) & 3) * 64;
#pragma unroll
            for (int i = 0; i < 4; ++i) {
                int chunk = tid + 512 * i;
                int j = chunk >> 3, kb = chunk & 7;
                streg[i] = *reinterpret_cast<const uint4*>(wsrc + (size_t)j * DN + k0 + kb * 8);
            }
        }
        {
            char* wl = (char*)wl4[cur];
            int sl = st & 3;
#pragma unroll
            for (int kk = 0; kk < 2; ++kk) {
                int ks = sl * 2 + kk;
                int off = (kk * 4 + g) * 16;
#pragma unroll
                for (int t = 0; t < 16; ++t) {
                    int j = t * 16 + c0;
                    int addr = (j * 128 + off) ^ ((j & 7) << 4);
                    short8 bfr = *reinterpret_cast<const short8*>(wl + addr);
                    acc[t] = __builtin_amdgcn_mfma_f32_16x16x32_bf16(ahi[ks], bfr, acc[t], 0, 0, 0);
                    if (st < 4)
                        acc[t] = __builtin_amdgcn_mfma_f32_16x16x32_bf16(alo[ks], bfr, acc[t], 0, 0, 0);
                }
            }
        }
        if (st < 7) {
#pragma unroll
            for (int i = 0; i < 4; ++i) {
                int chunk = tid + 512 * i;
                int j = chunk >> 3, kb = chunk & 7;
                int dst = ((j * 128 + kb * 16) ^ ((j & 7) << 4)) >> 4;
                wl4[cur ^ 1][dst] = streg[i];
            }
        }
        __syncthreads();
    }

    // epilogue: bias + LayerNorm + SiLU (fp32)
#pragma unroll
    for (int t = 0; t < 16; ++t) {
        float bb = bias[t * 16 + c0];
#pragma unroll
        for (int r = 0; r < 4; ++r) acc[t][r] += bb;
    }

    float s[4] = {0.f, 0.f, 0.f, 0.f};
#pragma unroll
    for (int t = 0; t < 16; ++t)
#pragma unroll
        for (int r = 0; r < 4; ++r) s[r] += acc[t][r];
#pragma unroll
    for (int r = 0; r < 4; ++r) {
#pragma unroll
        for (int m = 1; m < 16; m <<= 1) s[r] += __shfl_xor(s[r], m);
        s[r] *= (1.f / DN);
    }
    float vv[4] = {0.f, 0.f, 0.f, 0.f};
#pragma unroll
    for (int t = 0; t < 16; ++t)
#pragma unroll
        for (int r = 0; r < 4; ++r) { float d = acc[t][r] - s[r]; vv[r] += d * d; }
#pragma unroll
    for (int r = 0; r < 4; ++r) {
#pragma unroll
        for (int m = 1; m < 16; m <<= 1) vv[r] += __shfl_xor(vv[r], m);
        vv[r] = rsqrtf(vv[r] * (1.f / DN) + LN_EPS);
    }

    float gvv[16], btt[16];
#pragma unroll
    for (int t = 0; t < 16; ++t) {
        gvv[t] = gam[t * 16 + c0];
        btt[t] = bet[t * 16 + c0];
    }
#pragma unroll
    for (int r = 0; r < 4; ++r) {
        int row = n0 + w * 16 + g * 4 + r;
        if (row >= N) continue;
#pragma unroll
        for (int t = 0; t < 16; ++t) {
            float hn = (acc[t][r] - s[r]) * vv[r] * gvv[t] + btt[t];
            float sil = hn / (1.f + __expf(-hn));
            size_t o = (size_t)row * DN + t * 16 + c0;
            outf[o] = sil;
            if (outb) outb[o] = f2bf(sil);
        }
    }
}

extern "C" void kernel_launch(void* const* d_in, const int* in_sizes, int n_in,
                              void* d_out, int out_size, void* d_ws, size_t ws_size,
                              hipStream_t stream) {
    const float* x  = (const float*)d_in[0];
    const int*   ei = (const int*)d_in[1];
    const float* W0 = (const float*)d_in[2];
    const float* b0 = (const float*)d_in[3];
    const float* g0 = (const float*)d_in[4];
    const float* be0 = (const float*)d_in[5];
    const float* W1 = (const float*)d_in[6];
    const float* b1 = (const float*)d_in[7];
    const float* g1 = (const float*)d_in[8];
    const float* be1 = (const float*)d_in[9];
    float* out = (float*)d_out;
    ushort* outp = (ushort*)d_out;              // packed split-y view of d_out

    int N = in_sizes[0] / DN;
    int E = in_sizes[1] / 2;
    int nb = (N + 63) >> BSHIFT;                // buckets (<= 1024 for N <= 65536)

    // workspace: rp | part | bcnt | boff | bcur | brec | csr | xb | W splits (~40 MB)
    char* ws = (char*)d_ws;
    size_t off = 0;
    auto alloc = [&](size_t bytes) { void* p = ws + off;
                                     off = (off + bytes + 255) & ~(size_t)255; return p; };
    int* rp      = (int*)alloc((size_t)(N + 1) * 4);
    int* part    = (int*)alloc(256 * 4);
    int* bcnt    = (int*)alloc(1024 * 4);
    int* boff    = (int*)alloc(1025 * 4);
    int* bcur    = (int*)alloc(1024 * 4);
    uint* brec   = (uint*)alloc((size_t)E * 4);
    int* csr_c   = (int*)alloc((size_t)E * 4);
    ushort* xb   = (ushort*)alloc((size_t)N * DN * 2);
    ushort* whi0 = (ushort*)alloc((size_t)DN * DN * 2);
    ushort* wlo0 = (ushort*)alloc((size_t)DN * DN * 2);
    ushort* whi1 = (ushort*)alloc((size_t)DN * DN * 2);
    ushort* wlo1 = (ushort*)alloc((size_t)DN * DN * 2);

    int eblocks = (E + 255) / 256;
    int nblocks = (N + 255) / 256;   // 196 <= 256
    int ablocks = (N + 3) / 4;
    int gblocks = (N + 127) / 128;

    // CSR build (bucketed counting sort)
    hipMemsetAsync(rp, 0, (size_t)(N + 1) * 4, stream);
    hipMemsetAsync(bcnt, 0, 1024 * 4, stream);
    deg_bucket_count<<<1024, 256, 0, stream>>>(ei, rp, bcnt, E);
    scan_buckets<<<1, 256, 0, stream>>>(bcnt, boff, bcur, nb);
    scan_phase1<<<nblocks, 256, 0, stream>>>(rp, part, N);
    scan_phase2<<<1, 256, 0, stream>>>(part, nblocks);
    scan_phase3<<<nblocks, 256, 0, stream>>>(rp, part, N, E);
    bucket_fill<<<eblocks, 256, 0, stream>>>(ei, bcur, brec, E);
    csr_from_buckets<<<nb, 256, 0, stream>>>(brec, boff, rp, csr_c, N);

    // casts
    cast_f32_bf16<<<(N * DN / 8 + 255) / 256, 256, 0, stream>>>(x, xb, N * DN / 8);
    cast_split<<<(DN * DN / 4 + 255) / 256, 256, 0, stream>>>(W0, whi0, wlo0, DN * DN / 4);
    cast_split<<<(DN * DN / 4 + 255) / 256, 256, 0, stream>>>(W1, whi1, wlo1, DN * DN / 4);

    // layer 1: y1 packed into d_out; gemm in-place -> h1 fp32 (d_out) + h1 bf16 (xb)
    aggregate_packed<<<ablocks, 256, 0, stream>>>(x, xb, rp, csr_c, outp, N);
    gemm_ln_silu_mfma<<<gblocks, 512, 0, stream>>>(outp, whi0, wlo0,
                                                   b0, g0, be0, out, xb, N);
    // layer 2: self fp32 from d_out, neighbors bf16 from xb; gemm in-place -> final
    aggregate_packed<<<ablocks, 256, 0, stream>>>(out, xb, rp, csr_c, outp, N);
    gemm_ln_silu_mfma<<<gblocks, 512, 0, stream>>>(outp, whi1, wlo1,
                                                   b1, g1, be1, out, nullptr, N);
}

// Round 10
// 497.487 us; speedup vs baseline: 1.6642x; 1.6642x over previous
//
#include <hip/hip_runtime.h>
#include <math.h>

#define DN 256
#define LN_EPS 1e-5f

using f32x4  = __attribute__((ext_vector_type(4))) float;
using short8 = __attribute__((ext_vector_type(8))) short;

__device__ __forceinline__ ushort f2bf(float f) {
    uint u = __float_as_uint(f);
    u += 0x7fff + ((u >> 16) & 1);           // round-to-nearest-even
    return (ushort)(u >> 16);
}
__device__ __forceinline__ float bf2f(ushort h) { return __uint_as_float((uint)h << 16); }
__device__ __forceinline__ float bf_lo(uint u) { return __uint_as_float(u << 16); }
__device__ __forceinline__ float bf_hi(uint u) { return __uint_as_float(u & 0xffff0000u); }

// ---------------- x -> bf16 cast ----------------
__global__ __launch_bounds__(256) void cast_f32_bf16(const float* __restrict__ src,
                                                     ushort* __restrict__ dst, int n8) {
    int i = blockIdx.x * 256 + threadIdx.x;
    if (i >= n8) return;
    float4 a = reinterpret_cast<const float4*>(src)[2 * i];
    float4 b = reinterpret_cast<const float4*>(src)[2 * i + 1];
    uint4 o;
    o.x = (uint)f2bf(a.x) | ((uint)f2bf(a.y) << 16);
    o.y = (uint)f2bf(a.z) | ((uint)f2bf(a.w) << 16);
    o.z = (uint)f2bf(b.x) | ((uint)f2bf(b.y) << 16);
    o.w = (uint)f2bf(b.z) | ((uint)f2bf(b.w) << 16);
    reinterpret_cast<uint4*>(dst)[i] = o;
}

// ---------------- W split cast: f32 -> bf16 hi + bf16 lo ----------------
__global__ __launch_bounds__(256) void cast_split(const float* __restrict__ src,
                                                  ushort* __restrict__ hi,
                                                  ushort* __restrict__ lo, int n4) {
    int i = blockIdx.x * 256 + threadIdx.x;
    if (i >= n4) return;
    float4 a = reinterpret_cast<const float4*>(src)[i];
    ushort h0 = f2bf(a.x), h1 = f2bf(a.y), h2 = f2bf(a.z), h3 = f2bf(a.w);
    uint2 ho, lu;
    ho.x = (uint)h0 | ((uint)h1 << 16);
    ho.y = (uint)h2 | ((uint)h3 << 16);
    lu.x = (uint)f2bf(a.x - bf2f(h0)) | ((uint)f2bf(a.y - bf2f(h1)) << 16);
    lu.y = (uint)f2bf(a.z - bf2f(h2)) | ((uint)f2bf(a.w - bf2f(h3)) << 16);
    reinterpret_cast<uint2*>(hi)[i] = ho;
    reinterpret_cast<uint2*>(lo)[i] = lu;
}

// ---------------- CSR construction ----------------
__global__ __launch_bounds__(256) void deg_count(const int* __restrict__ ei,
                                                 int* __restrict__ rp, int E) {
    int e = blockIdx.x * 256 + threadIdx.x;
    if (e < E) atomicAdd(&rp[ei[e]], 1);
}

// 3-phase parallel exclusive scan of rp[0..N) (in place); phase3 also copies
// the scanned offsets into rcur (fill cursors) and sets rp[N]=E.
__global__ __launch_bounds__(256) void scan_phase1(int* __restrict__ rp,
                                                   int* __restrict__ part, int N) {
    __shared__ int wsum[4];
    int tid = threadIdx.x, lane = tid & 63, w = tid >> 6;
    int i = blockIdx.x * 256 + tid;
    int v = (i < N) ? rp[i] : 0;
    int s = v;
#pragma unroll
    for (int m = 1; m < 64; m <<= 1) {
        int t = __shfl_up(s, m);
        if (lane >= m) s += t;
    }
    if (lane == 63) wsum[w] = s;
    __syncthreads();
    int woff = 0;
    for (int k = 0; k < w; ++k) woff += wsum[k];
    if (i < N) rp[i] = woff + s - v;
    if (tid == 255) part[blockIdx.x] = woff + s;
}

__global__ __launch_bounds__(256) void scan_phase2(int* __restrict__ part, int nblk) {
    __shared__ int wsum[4];
    int tid = threadIdx.x, lane = tid & 63, w = tid >> 6;
    int v = (tid < nblk) ? part[tid] : 0;
    int s = v;
#pragma unroll
    for (int m = 1; m < 64; m <<= 1) {
        int t = __shfl_up(s, m);
        if (lane >= m) s += t;
    }
    if (lane == 63) wsum[w] = s;
    __syncthreads();
    int woff = 0;
    for (int k = 0; k < w; ++k) woff += wsum[k];
    if (tid < nblk) part[tid] = woff + s - v;
}

__global__ __launch_bounds__(256) void scan_phase3(int* __restrict__ rp,
                                                   const int* __restrict__ part,
                                                   int* __restrict__ rcur,
                                                   int N, int E) {
    int i = blockIdx.x * 256 + threadIdx.x;
    if (i < N) {
        int v = rp[i] + part[blockIdx.x];
        rp[i] = v;
        rcur[i] = v;
    }
    if (blockIdx.x == 0 && threadIdx.x == 0) rp[N] = E;
}

// XCD-partitioned CSR fill: group s = blockIdx%8 handles row range
// [s*N/8, (s+1)*N/8). With the round-robin block->XCD mapping, all writers of
// a given csr line sit on one XCD -> dirty lines coalesce in that XCD's L2
// instead of write-through (round-8 csr_fill: 100MB HBM writes for 6.4MB data).
// Correctness does NOT depend on the mapping; worst case is round-8 perf.
__global__ __launch_bounds__(256) void csr_fill_xcd(const int* __restrict__ ei,
                                                    int* __restrict__ rcur,
                                                    int* __restrict__ csr_col,
                                                    int E, int N, int gblk) {
    int s  = blockIdx.x & 7;
    int gi = blockIdx.x >> 3;
    int r_lo = (int)(((long long)s * N) >> 3);
    int r_hi = (int)(((long long)(s + 1) * N) >> 3);
    int stride = gblk * 256;
    for (int e = gi * 256 + threadIdx.x; e < E; e += stride) {
        int r = ei[e];
        if (r < r_lo || r >= r_hi) continue;
        int pos = atomicAdd(&rcur[r], 1);
        csr_col[pos] = ei[E + e];
    }
}

// ---------------- aggregation: y = self(fp32) + mean(neighbors bf16) ----------------
// rp is a clean exclusive scan with rp[N]=E. Writes split bf16 PACKED rows
// [256 hi][256 lo] (1024B = fp32 row). out_packed may alias xf_self.
__global__ __launch_bounds__(256) void aggregate_packed(const float* xf_self,
                                                        const ushort* __restrict__ xb_neigh,
                                                        const int* __restrict__ rp,
                                                        const int* __restrict__ csr_col,
                                                        ushort* out_packed, int N) {
    int wid  = (blockIdx.x * 256 + threadIdx.x) >> 6;
    int lane = threadIdx.x & 63;
    if (wid >= N) return;
    int start = rp[wid];
    int end   = rp[wid + 1];

    float4 xv = reinterpret_cast<const float4*>(xf_self + (size_t)wid * DN)[lane];

    float a0 = 0.f, a1 = 0.f, a2 = 0.f, a3 = 0.f;
    int j = start;
    for (; j + 8 <= end; j += 8) {
        uint2 v[8];
#pragma unroll
        for (int q = 0; q < 8; ++q) {
            int c = csr_col[j + q];
            v[q] = *reinterpret_cast<const uint2*>(xb_neigh + (size_t)c * DN + lane * 4);
        }
#pragma unroll
        for (int q = 0; q < 8; ++q) {
            a0 += bf_lo(v[q].x); a1 += bf_hi(v[q].x);
            a2 += bf_lo(v[q].y); a3 += bf_hi(v[q].y);
        }
    }
    for (; j < end; ++j) {
        int c = csr_col[j];
        uint2 v = *reinterpret_cast<const uint2*>(xb_neigh + (size_t)c * DN + lane * 4);
        a0 += bf_lo(v.x); a1 += bf_hi(v.x); a2 += bf_lo(v.y); a3 += bf_hi(v.y);
    }
    int deg = end - start;
    float inv = (deg > 0) ? 1.0f / (float)deg : 0.0f;
    float y0 = xv.x + a0 * inv, y1 = xv.y + a1 * inv;
    float y2 = xv.z + a2 * inv, y3 = xv.w + a3 * inv;
    ushort h0 = f2bf(y0), h1 = f2bf(y1), h2 = f2bf(y2), h3 = f2bf(y3);
    uint2 ho, lu;
    ho.x = (uint)h0 | ((uint)h1 << 16);
    ho.y = (uint)h2 | ((uint)h3 << 16);
    lu.x = (uint)f2bf(y0 - bf2f(h0)) | ((uint)f2bf(y1 - bf2f(h1)) << 16);
    lu.y = (uint)f2bf(y2 - bf2f(h2)) | ((uint)f2bf(y3 - bf2f(h3)) << 16);
    ushort* row = out_packed + (size_t)wid * 512;
    *reinterpret_cast<uint2*>(row + lane * 4) = ho;          // hi section [0,256)
    *reinterpret_cast<uint2*>(row + 256 + lane * 4) = lu;    // lo section [256,512)
}

// ---------------- split-precision MFMA GEMM + LayerNorm + SiLU ----------------
// h = (yhi+ylo) @ (Whi+Wlo)^T + b, dropping only the ylo*Wlo (eps^2) term.
// 512 threads = 8 waves, 128 rows/block. W in 8 x 32KB K-slices (4 hi + 4 lo),
// double-buffered ping-pong LDS, 1 barrier per slice, loads overlap MFMA.
__global__ __launch_bounds__(512) void gemm_ln_silu_mfma(
        const ushort* yb, const ushort* __restrict__ whi, const ushort* __restrict__ wlo,
        const float* __restrict__ bias, const float* __restrict__ gam,
        const float* __restrict__ bet,
        float* outf, ushort* __restrict__ outb, int N) {
    __shared__ uint4 wl4[2][2048];              // 2 x 32 KB ping-pong

    int tid = threadIdx.x;
    int w = tid >> 6, lane = tid & 63;
    int g = lane >> 4, c0 = lane & 15;
    int n0 = blockIdx.x * 128;

    int arow = n0 + w * 16 + c0;
    bool av = arow < N;
    const ushort* ah = yb + (size_t)arow * 512 + g * 8;
    short8 zz = {0, 0, 0, 0, 0, 0, 0, 0};
    short8 ahi[8], alo[8];
#pragma unroll
    for (int kk = 0; kk < 8; ++kk) {
        ahi[kk] = av ? *reinterpret_cast<const short8*>(ah + kk * 32) : zz;
        alo[kk] = av ? *reinterpret_cast<const short8*>(ah + 256 + kk * 32) : zz;
    }

    f32x4 acc[16];
#pragma unroll
    for (int t = 0; t < 16; ++t) acc[t] = (f32x4){0.f, 0.f, 0.f, 0.f};

    uint4 streg[4];
#pragma unroll
    for (int i = 0; i < 4; ++i) {
        int chunk = tid + 512 * i;
        int j = chunk >> 3, kb = chunk & 7;
        streg[i] = *reinterpret_cast<const uint4*>(whi + (size_t)j * DN + kb * 8);
    }
#pragma unroll
    for (int i = 0; i < 4; ++i) {
        int chunk = tid + 512 * i;
        int j = chunk >> 3, kb = chunk & 7;
        int dst = ((j * 128 + kb * 16) ^ ((j & 7) << 4)) >> 4;
        wl4[0][dst] = streg[i];
    }
    __syncthreads();

#pragma unroll
    for (int st = 0; st < 8; ++st) {
        int cur = st & 1;
        if (st < 7) {
            const ushort* wsrc = (st + 1 < 4) ? whi : wlo;
            int k0 = ((st + 1) & 3) * 64;
#pragma unroll
            for (int i = 0; i < 4; ++i) {
                int chunk = tid + 512 * i;
                int j = chunk >> 3, kb = chunk & 7;
                streg[i] = *reinterpret_cast<const uint4*>(wsrc + (size_t)j * DN + k0 + kb * 8);
            }
        }
        {
            char* wl = (char*)wl4[cur];
            int sl = st & 3;
#pragma unroll
            for (int kk = 0; kk < 2; ++kk) {
                int ks = sl * 2 + kk;
                int off = (kk * 4 + g) * 16;
#pragma unroll
                for (int t = 0; t < 16; ++t) {
                    int j = t * 16 + c0;
                    int addr = (j * 128 + off) ^ ((j & 7) << 4);
                    short8 bfr = *reinterpret_cast<const short8*>(wl + addr);
                    acc[t] = __builtin_amdgcn_mfma_f32_16x16x32_bf16(ahi[ks], bfr, acc[t], 0, 0, 0);
                    if (st < 4)
                        acc[t] = __builtin_amdgcn_mfma_f32_16x16x32_bf16(alo[ks], bfr, acc[t], 0, 0, 0);
                }
            }
        }
        if (st < 7) {
#pragma unroll
            for (int i = 0; i < 4; ++i) {
                int chunk = tid + 512 * i;
                int j = chunk >> 3, kb = chunk & 7;
                int dst = ((j * 128 + kb * 16) ^ ((j & 7) << 4)) >> 4;
                wl4[cur ^ 1][dst] = streg[i];
            }
        }
        __syncthreads();
    }

    // epilogue: bias + LayerNorm + SiLU (fp32)
#pragma unroll
    for (int t = 0; t < 16; ++t) {
        float bb = bias[t * 16 + c0];
#pragma unroll
        for (int r = 0; r < 4; ++r) acc[t][r] += bb;
    }

    float s[4] = {0.f, 0.f, 0.f, 0.f};
#pragma unroll
    for (int t = 0; t < 16; ++t)
#pragma unroll
        for (int r = 0; r < 4; ++r) s[r] += acc[t][r];
#pragma unroll
    for (int r = 0; r < 4; ++r) {
#pragma unroll
        for (int m = 1; m < 16; m <<= 1) s[r] += __shfl_xor(s[r], m);
        s[r] *= (1.f / DN);
    }
    float vv[4] = {0.f, 0.f, 0.f, 0.f};
#pragma unroll
    for (int t = 0; t < 16; ++t)
#pragma unroll
        for (int r = 0; r < 4; ++r) { float d = acc[t][r] - s[r]; vv[r] += d * d; }
#pragma unroll
    for (int r = 0; r < 4; ++r) {
#pragma unroll
        for (int m = 1; m < 16; m <<= 1) vv[r] += __shfl_xor(vv[r], m);
        vv[r] = rsqrtf(vv[r] * (1.f / DN) + LN_EPS);
    }

    float gvv[16], btt[16];
#pragma unroll
    for (int t = 0; t < 16; ++t) {
        gvv[t] = gam[t * 16 + c0];
        btt[t] = bet[t * 16 + c0];
    }
#pragma unroll
    for (int r = 0; r < 4; ++r) {
        int row = n0 + w * 16 + g * 4 + r;
        if (row >= N) continue;
#pragma unroll
        for (int t = 0; t < 16; ++t) {
            float hn = (acc[t][r] - s[r]) * vv[r] * gvv[t] + btt[t];
            float sil = hn / (1.f + __expf(-hn));
            size_t o = (size_t)row * DN + t * 16 + c0;
            outf[o] = sil;
            if (outb) outb[o] = f2bf(sil);
        }
    }
}

extern "C" void kernel_launch(void* const* d_in, const int* in_sizes, int n_in,
                              void* d_out, int out_size, void* d_ws, size_t ws_size,
                              hipStream_t stream) {
    const float* x  = (const float*)d_in[0];
    const int*   ei = (const int*)d_in[1];
    const float* W0 = (const float*)d_in[2];
    const float* b0 = (const float*)d_in[3];
    const float* g0 = (const float*)d_in[4];
    const float* be0 = (const float*)d_in[5];
    const float* W1 = (const float*)d_in[6];
    const float* b1 = (const float*)d_in[7];
    const float* g1 = (const float*)d_in[8];
    const float* be1 = (const float*)d_in[9];
    float* out = (float*)d_out;
    ushort* outp = (ushort*)d_out;              // packed split-y view of d_out

    int N = in_sizes[0] / DN;
    int E = in_sizes[1] / 2;

    // workspace: rp | part | rcur | csr | xb | W splits (~33 MB)
    char* ws = (char*)d_ws;
    size_t off = 0;
    auto alloc = [&](size_t bytes) { void* p = ws + off;
                                     off = (off + bytes + 255) & ~(size_t)255; return p; };
    int* rp      = (int*)alloc((size_t)(N + 1) * 4);
    int* part    = (int*)alloc(256 * 4);
    int* rcur    = (int*)alloc((size_t)N * 4);
    int* csr_c   = (int*)alloc((size_t)E * 4);
    ushort* xb   = (ushort*)alloc((size_t)N * DN * 2);
    ushort* whi0 = (ushort*)alloc((size_t)DN * DN * 2);
    ushort* wlo0 = (ushort*)alloc((size_t)DN * DN * 2);
    ushort* whi1 = (ushort*)alloc((size_t)DN * DN * 2);
    ushort* wlo1 = (ushort*)alloc((size_t)DN * DN * 2);

    int eblocks = (E + 255) / 256;
    int nblocks = (N + 255) / 256;   // 196 <= 256
    int ablocks = (N + 3) / 4;
    int gblocks = (N + 127) / 128;
    int fgrp    = 104;               // fill blocks per XCD group (8*104=832 total)

    // CSR build
    hipMemsetAsync(rp, 0, (size_t)(N + 1) * 4, stream);
    deg_count<<<eblocks, 256, 0, stream>>>(ei, rp, E);
    scan_phase1<<<nblocks, 256, 0, stream>>>(rp, part, N);
    scan_phase2<<<1, 256, 0, stream>>>(part, nblocks);
    scan_phase3<<<nblocks, 256, 0, stream>>>(rp, part, rcur, N, E);
    csr_fill_xcd<<<8 * fgrp, 256, 0, stream>>>(ei, rcur, csr_c, E, N, fgrp);

    // casts
    cast_f32_bf16<<<(N * DN / 8 + 255) / 256, 256, 0, stream>>>(x, xb, N * DN / 8);
    cast_split<<<(DN * DN / 4 + 255) / 256, 256, 0, stream>>>(W0, whi0, wlo0, DN * DN / 4);
    cast_split<<<(DN * DN / 4 + 255) / 256, 256, 0, stream>>>(W1, whi1, wlo1, DN * DN / 4);

    // layer 1: y1 packed into d_out; gemm in-place -> h1 fp32 (d_out) + h1 bf16 (xb)
    aggregate_packed<<<ablocks, 256, 0, stream>>>(x, xb, rp, csr_c, outp, N);
    gemm_ln_silu_mfma<<<gblocks, 512, 0, stream>>>(outp, whi0, wlo0,
                                                   b0, g0, be0, out, xb, N);
    // layer 2: self fp32 from d_out, neighbors bf16 from xb; gemm in-place -> final
    aggregate_packed<<<ablocks, 256, 0, stream>>>(out, xb, rp, csr_c, outp, N);
    gemm_ln_silu_mfma<<<gblocks, 512, 0, stream>>>(outp, whi1, wlo1,
                                                   b1, g1, be1, out, nullptr, N);
}